// Round 3
// baseline (420.573 us; speedup 1.0000x reference)
//
#include <hip/hip_runtime.h>
#include <hip/hip_bf16.h>

typedef __hip_bfloat16 bf16;

#define FIN 128
#define HD 256
#define NA 8

__device__ __forceinline__ float b2f(bf16 v) { return __bfloat162float(v); }

struct SegOffs { int o[10]; };  // o[t] = start of float tensor t in dstf; o[9] = total

// ---------------- runtime wire-dtype detection ----------------
// flags[0] = 1 if float tensors are f32 on the wire (else bf16)
// flags[1] = 1 if edge_index is int64 on the wire (else int32)
__global__ void detect_kernel(const unsigned short* xw, const int* ew, int* flags,
                              int nx_halfwords, int ne_words) {
  __shared__ int cnt0, cnt1;
  if (threadIdx.x == 0) { cnt0 = 0; cnt1 = 0; }
  __syncthreads();
  int outl = 0, zeros = 0;
  int nx = nx_halfwords < 4096 ? nx_halfwords : 4096;
  int ne = ne_words < 4096 ? ne_words : 4096;
  for (int i = threadIdx.x; i < nx; i += 256) {
    unsigned u = xw[i];
    unsigned ex = (u >> 7) & 0xFF;      // bf16 exponent field
    if (ex >= 134) outl++;              // |v| >= 128: impossible for N(0,1) bf16
  }
  for (int i = threadIdx.x; i < ne; i += 256) {
    if ((i & 1) && ew[i] == 0) zeros++; // high words of small int64s are 0
  }
  atomicAdd(&cnt0, outl);
  atomicAdd(&cnt1, zeros);
  __syncthreads();
  if (threadIdx.x == 0) {
    flags[0] = (cnt0 > 100) ? 1 : 0;
    flags[1] = (cnt1 > 1000) ? 1 : 0;
  }
}

// ---------------- convert all float tensors -> contiguous f32 ----------------
__global__ void cvt_all_kernel(const void* t0, const void* t1, const void* t2,
                               const void* t3, const void* t4, const void* t5,
                               const void* t6, const void* t7, const void* t8,
                               SegOffs so, float* dstf, const int* flags) {
  int i = blockIdx.x * blockDim.x + threadIdx.x;
  if (i >= so.o[9]) return;
  const bool f32w = flags[0] != 0;
  const void* srcs[9] = {t0, t1, t2, t3, t4, t5, t6, t7, t8};
  int t = 0;
  #pragma unroll
  for (int k = 1; k < 9; ++k) t += (i >= so.o[k]) ? 1 : 0;
  int off = i - so.o[t];
  const void* s = srcs[t];
  dstf[i] = f32w ? ((const float*)s)[off] : b2f(((const bf16*)s)[off]);
}

__global__ void cvt_edges_kernel(const int* ei, int* src, int* dst, int E,
                                 const int* flags) {
  int e = blockIdx.x * blockDim.x + threadIdx.x;
  if (e >= E) return;
  if (flags[1]) {            // int64 wire: low words at even positions
    src[e] = ei[2 * e];
    dst[e] = ei[2 * (E + e)];
  } else {
    src[e] = ei[e];
    dst[e] = ei[E + e];
  }
}

// ---------------- degree / CSR build ----------------
__global__ void count_kernel(const int* __restrict__ dst, int* __restrict__ count, int E) {
  int e = blockIdx.x * blockDim.x + threadIdx.x;
  if (e < E) atomicAdd(&count[dst[e]], 1);
}

__global__ void dinv_kernel(const int* __restrict__ count, float* __restrict__ dinv, int n) {
  int i = blockIdx.x * blockDim.x + threadIdx.x;
  if (i < n) dinv[i] = rsqrtf((float)count[i] + 1.0f);  // +1 = self loop
}

__global__ void scan_kernel(const int* __restrict__ count, int* __restrict__ offs, int n) {
  __shared__ int lds[256];
  const int tid = threadIdx.x;
  int base = 0;
  for (int start = 0; start < n; start += 256) {
    int i = start + tid;
    int v = (i < n) ? count[i] : 0;
    lds[tid] = v;
    __syncthreads();
    for (int off = 1; off < 256; off <<= 1) {
      int t = (tid >= off) ? lds[tid - off] : 0;
      __syncthreads();
      lds[tid] += t;
      __syncthreads();
    }
    if (i < n) offs[i] = base + lds[tid] - v;
    base += lds[255];
    __syncthreads();
  }
  if (tid == 0) offs[n] = base;
}

__global__ void cursor_kernel(const int* __restrict__ offs, int* __restrict__ cursor, int n) {
  int i = blockIdx.x * blockDim.x + threadIdx.x;
  if (i < n) cursor[i] = offs[i];
}

__global__ void fill_kernel(const int* __restrict__ src, const int* __restrict__ dst,
                            const float* __restrict__ dinv, int* __restrict__ cursor,
                            int* __restrict__ csr_src, float* __restrict__ csr_w, int E) {
  int e = blockIdx.x * blockDim.x + threadIdx.x;
  if (e < E) {
    int s = src[e], d = dst[e];
    int p = atomicAdd(&cursor[d], 1);
    csr_src[p] = s;
    csr_w[p] = dinv[s] * dinv[d];
  }
}

// ---------------- GEMM: [N x K] @ [K x 256] -> f32 [N x 256] ----------------
template<int K, bool BIAS, bool RELU>
__global__ void gemm256(const float* __restrict__ A, const float* __restrict__ B,
                        const float* __restrict__ bias, float* __restrict__ C, int N) {
  __shared__ float a_lds[16 * K];
  const int tid = threadIdx.x;
  const int row0 = blockIdx.x * 16;

  for (int idx = tid; idx < 16 * K; idx += 256) {
    int r = idx / K;
    int k = idx - r * K;
    int gr = row0 + r;
    a_lds[idx] = (gr < N) ? A[(size_t)gr * K + k] : 0.f;
  }
  __syncthreads();

  const int jp = (tid & 127) * 2;   // column pair
  const int r0 = (tid >> 7) * 8;    // row half
  float acc0[8] = {0.f, 0.f, 0.f, 0.f, 0.f, 0.f, 0.f, 0.f};
  float acc1[8] = {0.f, 0.f, 0.f, 0.f, 0.f, 0.f, 0.f, 0.f};

  for (int k = 0; k < K; ++k) {
    float2 bv = *reinterpret_cast<const float2*>(&B[(size_t)k * 256 + jp]);
    #pragma unroll
    for (int r = 0; r < 8; ++r) {
      float a = a_lds[(r0 + r) * K + k];
      acc0[r] += a * bv.x;
      acc1[r] += a * bv.y;
    }
  }

  float bb0 = 0.f, bb1 = 0.f;
  if (BIAS) { bb0 = bias[jp]; bb1 = bias[jp + 1]; }
  #pragma unroll
  for (int r = 0; r < 8; ++r) {
    int gr = row0 + r0 + r;
    if (gr < N) {
      float v0 = acc0[r] + bb0, v1 = acc1[r] + bb1;
      if (RELU) { v0 = fmaxf(v0, 0.f); v1 = fmaxf(v1, 0.f); }
      *reinterpret_cast<float2*>(&C[(size_t)gr * 256 + jp]) = make_float2(v0, v1);
    }
  }
}

// ---------------- GCN aggregation (gather by dst), fused bias + ReLU --------
__global__ void agg_kernel(const float* __restrict__ tmp, const int* __restrict__ offs,
                           const int* __restrict__ csr_src, const float* __restrict__ csr_w,
                           const float* __restrict__ dinv, const float* __restrict__ bias,
                           float* __restrict__ out) {
  const int i = blockIdx.x;   // node
  const int j = threadIdx.x;  // feature 0..255
  float di = dinv[i];
  float acc = di * di * tmp[(size_t)i * 256 + j] + bias[j];
  int e = offs[i], e1 = offs[i + 1];
  for (; e < e1; ++e) {
    int s = csr_src[e];
    float w = csr_w[e];
    acc += w * tmp[(size_t)s * 256 + j];
  }
  out[(size_t)i * 256 + j] = fmaxf(acc, 0.f);
}

// ---------------- final projection: [N x 256] @ [256 x 8] + b ---------------
__global__ void gemm_out_kernel(const float* __restrict__ A, const float* __restrict__ B,
                                const float* __restrict__ bias, void* __restrict__ out,
                                int N, const int* flags) {
  __shared__ float w[HD * NA];
  __shared__ float bs[NA];
  const int tid = threadIdx.x;
  for (int idx = tid; idx < HD * NA; idx += 256) w[idx] = B[idx];
  if (tid < NA) bs[tid] = bias[tid];
  __syncthreads();
  int row = blockIdx.x * 32 + (tid >> 3);
  int j = tid & 7;
  if (row < N) {
    float acc = 0.f;
    #pragma unroll 4
    for (int k = 0; k < HD; ++k) acc += A[(size_t)row * HD + k] * w[k * NA + j];
    float v = acc + bs[j];
    if (flags[0]) ((float*)out)[(size_t)row * NA + j] = v;
    else          ((bf16*)out)[(size_t)row * NA + j] = __float2bfloat16(v);
  }
}

// ---------------- launch ----------------
extern "C" void kernel_launch(void* const* d_in, const int* in_sizes, int n_in,
                              void* d_out, int out_size, void* d_ws, size_t ws_size,
                              hipStream_t stream) {
  (void)n_in; (void)out_size; (void)ws_size;
  const void* x_raw  = d_in[0];
  const int*  ei_raw = (const int*)d_in[1];

  const int N = in_sizes[0] / FIN;
  const int E = in_sizes[1] / 2;

  // float-tensor segment offsets (dict order, skipping edge_index at idx 1)
  SegOffs so;
  int acc = 0;
  const int fidx[9] = {0, 2, 3, 4, 5, 6, 7, 8, 9};
  for (int t = 0; t < 9; ++t) { so.o[t] = acc; acc += in_sizes[fidx[t]]; }
  so.o[9] = acc;

  char* ws = (char*)d_ws;
  size_t off = 0;
  auto walloc = [&](size_t bytes) -> void* {
    void* p = ws + off;
    off = (off + bytes + 255) & ~(size_t)255;
    return p;
  };
  float* fbase   = (float*)walloc((size_t)acc * 4);
  int*   flags   = (int*)walloc(16);
  float* dinv    = (float*)walloc((size_t)N * 4);
  int*   count   = (int*)walloc((size_t)N * 4);
  int*   offs    = (int*)walloc((size_t)(N + 1) * 4);
  int*   cursor  = (int*)walloc((size_t)N * 4);
  int*   csr_src = (int*)walloc((size_t)E * 4);
  float* csr_w   = (float*)walloc((size_t)E * 4);
  int*   src32   = (int*)walloc((size_t)E * 4);
  int*   dst32   = (int*)walloc((size_t)E * 4);
  float* tmp     = (float*)walloc((size_t)N * HD * 4);
  float* aggb    = (float*)walloc((size_t)N * HD * 4);

  const float* xf   = fbase + so.o[0];
  const float* w1f  = fbase + so.o[1];
  const float* b1f  = fbase + so.o[2];
  const float* w2f  = fbase + so.o[3];
  const float* b2f  = fbase + so.o[4];
  const float* wh1f = fbase + so.o[5];
  const float* bh1f = fbase + so.o[6];
  const float* wh2f = fbase + so.o[7];
  const float* bh2f = fbase + so.o[8];

  detect_kernel<<<1, 256, 0, stream>>>((const unsigned short*)x_raw, ei_raw, flags,
                                       in_sizes[0], in_sizes[1]);

  cvt_all_kernel<<<(acc + 255) / 256, 256, 0, stream>>>(
      d_in[0], d_in[2], d_in[3], d_in[4], d_in[5], d_in[6], d_in[7], d_in[8], d_in[9],
      so, fbase, flags);

  const int eb = 256;
  const int eg = (E + eb - 1) / eb;
  cvt_edges_kernel<<<eg, eb, 0, stream>>>(ei_raw, src32, dst32, E, flags);

  hipMemsetAsync(count, 0, (size_t)N * 4, stream);
  count_kernel<<<eg, eb, 0, stream>>>(dst32, count, E);
  dinv_kernel<<<(N + 255) / 256, 256, 0, stream>>>(count, dinv, N);
  scan_kernel<<<1, 256, 0, stream>>>(count, offs, N);
  cursor_kernel<<<(N + 255) / 256, 256, 0, stream>>>(offs, cursor, N);
  fill_kernel<<<eg, eb, 0, stream>>>(src32, dst32, dinv, cursor, csr_src, csr_w, E);

  const int gb = (N + 15) / 16;
  gemm256<FIN, false, false><<<gb, 256, 0, stream>>>(xf,   w1f, nullptr, tmp, N);
  agg_kernel<<<N, 256, 0, stream>>>(tmp, offs, csr_src, csr_w, dinv, b1f, aggb);
  gemm256<HD,  false, false><<<gb, 256, 0, stream>>>(aggb, w2f, nullptr, tmp, N);
  agg_kernel<<<N, 256, 0, stream>>>(tmp, offs, csr_src, csr_w, dinv, b2f, aggb);
  gemm256<HD,  true,  true ><<<gb, 256, 0, stream>>>(aggb, wh1f, bh1f, tmp, N);
  gemm_out_kernel<<<(N + 31) / 32, 256, 0, stream>>>(tmp, wh2f, bh2f, d_out, N, flags);
}

// Round 5
// 342.059 us; speedup vs baseline: 1.2295x; 1.2295x over previous
//
#include <hip/hip_runtime.h>
#include <hip/hip_bf16.h>

typedef __hip_bfloat16 bf16;

#define FIN 128
#define HD 256
#define NA 8

__device__ __forceinline__ float b2f(bf16 v) { return __bfloat162float(v); }
__device__ __forceinline__ float bfbits(unsigned short b) {
  unsigned v = ((unsigned)b) << 16;
  return __uint_as_float(v);
}

struct SegOffs { int o[9]; };  // 8 weight tensors; o[8] = total

// ---------------- runtime wire-dtype detection ----------------
// flags[0] = 1 if float tensors are f32 on the wire (else bf16)
// flags[1] = 1 if edge_index is int64 on the wire (else int32)
__global__ void detect_kernel(const unsigned short* xw, const int* ew, int* flags,
                              int nx_halfwords, int ne_words) {
  __shared__ int cnt0, cnt1;
  if (threadIdx.x == 0) { cnt0 = 0; cnt1 = 0; }
  __syncthreads();
  int outl = 0, zeros = 0;
  int nx = nx_halfwords < 4096 ? nx_halfwords : 4096;
  int ne = ne_words < 4096 ? ne_words : 4096;
  for (int i = threadIdx.x; i < nx; i += 256) {
    unsigned u = xw[i];
    unsigned ex = (u >> 7) & 0xFF;
    if (ex >= 134) outl++;              // |v| >= 128: impossible for N(0,1) bf16
  }
  for (int i = threadIdx.x; i < ne; i += 256) {
    if ((i & 1) && ew[i] == 0) zeros++; // high words of small int64s
  }
  atomicAdd(&cnt0, outl);
  atomicAdd(&cnt1, zeros);
  __syncthreads();
  if (threadIdx.x == 0) {
    flags[0] = (cnt0 > 100) ? 1 : 0;
    flags[1] = (cnt1 > 1000) ? 1 : 0;
  }
}

// ---------------- convert weight tensors -> contiguous f32 ----------------
__global__ void cvt_w_kernel(const void* t0, const void* t1, const void* t2,
                             const void* t3, const void* t4, const void* t5,
                             const void* t6, const void* t7,
                             SegOffs so, float* dstf, const int* flags) {
  int i = blockIdx.x * blockDim.x + threadIdx.x;
  if (i >= so.o[8]) return;
  const bool f32w = flags[0] != 0;
  const void* srcs[8] = {t0, t1, t2, t3, t4, t5, t6, t7};
  int t = 0;
  #pragma unroll
  for (int k = 1; k < 8; ++k) t += (i >= so.o[k]) ? 1 : 0;
  int off = i - so.o[t];
  const void* s = srcs[t];
  dstf[i] = f32w ? ((const float*)s)[off] : b2f(((const bf16*)s)[off]);
}

// ---------------- edges: decode + degree count (fused) ----------------
__global__ void edges_count_kernel(const int* ei, int* src, int* dst, int E,
                                   const int* flags, int* count) {
  int e = blockIdx.x * blockDim.x + threadIdx.x;
  if (e >= E) return;
  int s, d;
  if (flags[1]) { s = ei[2 * e]; d = ei[2 * (E + e)]; }
  else          { s = ei[e];     d = ei[E + e]; }
  src[e] = s;
  dst[e] = d;
  atomicAdd(&count[d], 1);
}

__global__ void dinv_kernel(const int* __restrict__ count, float* __restrict__ dinv, int n) {
  int i = blockIdx.x * blockDim.x + threadIdx.x;
  if (i < n) dinv[i] = rsqrtf((float)count[i] + 1.0f);  // +1 = self loop
}

// ---------------- parallel exclusive scan (3 phases) ----------------
__global__ void scan1_kernel(const int* count, int* offs, int* partials, int n) {
  __shared__ int lds[256];
  int tid = threadIdx.x, i = blockIdx.x * 256 + tid;
  int v = (i < n) ? count[i] : 0;
  lds[tid] = v;
  __syncthreads();
  for (int off = 1; off < 256; off <<= 1) {
    int t = (tid >= off) ? lds[tid - off] : 0;
    __syncthreads();
    lds[tid] += t;
    __syncthreads();
  }
  if (i < n) offs[i] = lds[tid] - v;       // local exclusive
  if (tid == 255) partials[blockIdx.x] = lds[255];
}

__global__ void scan2_kernel(int* partials, int* offs, int nb, int n) {
  __shared__ int lds[64];
  int tid = threadIdx.x;
  int v = (tid < nb) ? partials[tid] : 0;
  lds[tid] = v;
  __syncthreads();
  for (int off = 1; off < 64; off <<= 1) {
    int t = (tid >= off) ? lds[tid - off] : 0;
    __syncthreads();
    lds[tid] += t;
    __syncthreads();
  }
  if (tid < nb) partials[tid] = lds[tid] - v;  // exclusive over block totals
  if (tid == 63) offs[n] = lds[63];            // grand total
}

__global__ void scan3_kernel(int* offs, const int* partials, int* cursor, int n) {
  int i = blockIdx.x * 256 + threadIdx.x;
  if (i < n) {
    int o = offs[i] + partials[blockIdx.x];
    offs[i] = o;
    cursor[i] = o;
  }
}

__global__ void fill_kernel(const int* __restrict__ src, const int* __restrict__ dst,
                            const float* __restrict__ dinv, int* __restrict__ cursor,
                            int* __restrict__ csr_src, float* __restrict__ csr_w, int E) {
  int e = blockIdx.x * blockDim.x + threadIdx.x;
  if (e < E) {
    int s = src[e], d = dst[e];
    int p = atomicAdd(&cursor[d], 1);
    csr_src[p] = s;
    csr_w[p] = dinv[s] * dinv[d];
  }
}

// ---------------- agg1: gather raw x (128 feats) -> xagg f32 ----------------
// one node per wave; lane holds feats {2*lane, 2*lane+1}
__global__ void agg1_kernel(const void* __restrict__ xraw, const int* __restrict__ offs,
                            const int* __restrict__ csr_src, const float* __restrict__ csr_w,
                            const float* __restrict__ dinv, float* __restrict__ out,
                            int n, const int* flags) {
  int wave = (blockIdx.x * blockDim.x + threadIdx.x) >> 6;
  int lane = threadIdx.x & 63;
  if (wave >= n) return;
  const bool f32w = flags[0] != 0;
  const int i = wave;

  auto loadrow = [&](int s) -> float2 {
    if (f32w) return ((const float2*)xraw)[(size_t)s * 64 + lane];
    unsigned u = ((const unsigned*)xraw)[(size_t)s * 32 + lane];
    return make_float2(bfbits((unsigned short)(u & 0xFFFF)),
                       bfbits((unsigned short)(u >> 16)));
  };

  float di = dinv[i];
  float s2 = di * di;
  float2 xi = loadrow(i);
  float ax = s2 * xi.x, ay = s2 * xi.y;

  int e = offs[i], e1 = offs[i + 1];
  if (e < e1) {
    int s0 = csr_src[e];
    float w0 = csr_w[e];
    float2 r0 = loadrow(s0);
    for (++e; e < e1; ++e) {
      int s1 = csr_src[e];
      float w1 = csr_w[e];
      float2 r1 = loadrow(s1);       // in flight while consuming r0
      ax += w0 * r0.x; ay += w0 * r0.y;
      w0 = w1; r0 = r1;
    }
    ax += w0 * r0.x; ay += w0 * r0.y;
  }
  ((float2*)out)[(size_t)i * 64 + lane] = make_float2(ax, ay);
}

// ---------------- agg2: gather f32 (256 feats), fused bias+relu ----------------
// one node per wave; lane holds a float4 slice (feats 4*lane..4*lane+3)
__global__ void agg2_kernel(const float* __restrict__ tmp, const int* __restrict__ offs,
                            const int* __restrict__ csr_src, const float* __restrict__ csr_w,
                            const float* __restrict__ dinv, const float* __restrict__ bias,
                            float* __restrict__ out, int n) {
  int wave = (blockIdx.x * blockDim.x + threadIdx.x) >> 6;
  int lane = threadIdx.x & 63;
  if (wave >= n) return;
  const int i = wave;

  float di = dinv[i];
  float s2 = di * di;
  float4 xi = ((const float4*)(tmp + (size_t)i * 256))[lane];
  float4 b4 = ((const float4*)bias)[lane];
  float a0 = s2 * xi.x + b4.x, a1 = s2 * xi.y + b4.y;
  float a2 = s2 * xi.z + b4.z, a3 = s2 * xi.w + b4.w;

  int e = offs[i], e1 = offs[i + 1];
  if (e < e1) {
    int s0 = csr_src[e];
    float w0 = csr_w[e];
    float4 r0 = ((const float4*)(tmp + (size_t)s0 * 256))[lane];
    for (++e; e < e1; ++e) {
      int s1 = csr_src[e];
      float w1 = csr_w[e];
      float4 r1 = ((const float4*)(tmp + (size_t)s1 * 256))[lane];
      a0 += w0 * r0.x; a1 += w0 * r0.y; a2 += w0 * r0.z; a3 += w0 * r0.w;
      w0 = w1; r0 = r1;
    }
    a0 += w0 * r0.x; a1 += w0 * r0.y; a2 += w0 * r0.z; a3 += w0 * r0.w;
  }
  float4 res = make_float4(fmaxf(a0, 0.f), fmaxf(a1, 0.f), fmaxf(a2, 0.f), fmaxf(a3, 0.f));
  ((float4*)(out + (size_t)i * 256))[lane] = res;
}

// ---------------- GEMM: [N x K] @ [K x 256] -> f32 [N x 256] ----------------
// 16 rows/block, 256 threads; thread = 4 rows x 4 cols (float4 B loads)
template<int K, bool BIAS, bool RELU>
__global__ void gemm256(const float* __restrict__ A, const float* __restrict__ B,
                        const float* __restrict__ bias, float* __restrict__ C, int N) {
  __shared__ float a_lds[16 * K];
  const int tid = threadIdx.x;
  const int row0 = blockIdx.x * 16;

  for (int idx = tid; idx < 16 * (K / 4); idx += 256) {
    int r = idx / (K / 4);
    int k4 = idx - r * (K / 4);
    int gr = row0 + r;
    float4 v = make_float4(0.f, 0.f, 0.f, 0.f);
    if (gr < N) v = ((const float4*)A)[(size_t)gr * (K / 4) + k4];
    ((float4*)a_lds)[idx] = v;
  }
  __syncthreads();

  const int jq = (tid & 63) * 4;   // col quad
  const int r0 = (tid >> 6) * 4;   // row quad (wave-uniform)
  float acc[4][4] = {};

  #pragma unroll 2
  for (int k = 0; k < K; ++k) {
    float4 bv = *reinterpret_cast<const float4*>(&B[(size_t)k * 256 + jq]);
    float a0 = a_lds[(r0 + 0) * K + k];
    float a1 = a_lds[(r0 + 1) * K + k];
    float a2 = a_lds[(r0 + 2) * K + k];
    float a3 = a_lds[(r0 + 3) * K + k];
    acc[0][0] += a0 * bv.x; acc[0][1] += a0 * bv.y; acc[0][2] += a0 * bv.z; acc[0][3] += a0 * bv.w;
    acc[1][0] += a1 * bv.x; acc[1][1] += a1 * bv.y; acc[1][2] += a1 * bv.z; acc[1][3] += a1 * bv.w;
    acc[2][0] += a2 * bv.x; acc[2][1] += a2 * bv.y; acc[2][2] += a2 * bv.z; acc[2][3] += a2 * bv.w;
    acc[3][0] += a3 * bv.x; acc[3][1] += a3 * bv.y; acc[3][2] += a3 * bv.z; acc[3][3] += a3 * bv.w;
  }

  float4 bb = make_float4(0.f, 0.f, 0.f, 0.f);
  if (BIAS) bb = *reinterpret_cast<const float4*>(&bias[jq]);
  #pragma unroll
  for (int r = 0; r < 4; ++r) {
    int gr = row0 + r0 + r;
    if (gr < N) {
      float4 v = make_float4(acc[r][0] + bb.x, acc[r][1] + bb.y,
                             acc[r][2] + bb.z, acc[r][3] + bb.w);
      if (RELU) {
        v.x = fmaxf(v.x, 0.f); v.y = fmaxf(v.y, 0.f);
        v.z = fmaxf(v.z, 0.f); v.w = fmaxf(v.w, 0.f);
      }
      *reinterpret_cast<float4*>(&C[(size_t)gr * 256 + jq]) = v;
    }
  }
}

// ---------------- final projection: [N x 256] @ [256 x 8] + b ---------------
__global__ void gemm_out_kernel(const float* __restrict__ A, const float* __restrict__ B,
                                const float* __restrict__ bias, void* __restrict__ out,
                                int N, const int* flags) {
  __shared__ float w[HD * NA];
  __shared__ float bs[NA];
  const int tid = threadIdx.x;
  for (int idx = tid; idx < HD * NA; idx += 256) w[idx] = B[idx];
  if (tid < NA) bs[tid] = bias[tid];
  __syncthreads();
  int row = blockIdx.x * 32 + (tid >> 3);
  int j = tid & 7;
  if (row < N) {
    float acc = 0.f;
    #pragma unroll 4
    for (int k = 0; k < HD; ++k) acc += A[(size_t)row * HD + k] * w[k * NA + j];
    float v = acc + bs[j];
    if (flags[0]) ((float*)out)[(size_t)row * NA + j] = v;
    else          ((bf16*)out)[(size_t)row * NA + j] = __float2bfloat16(v);
  }
}

// ---------------- launch ----------------
extern "C" void kernel_launch(void* const* d_in, const int* in_sizes, int n_in,
                              void* d_out, int out_size, void* d_ws, size_t ws_size,
                              hipStream_t stream) {
  (void)n_in; (void)out_size; (void)ws_size;
  const void* x_raw  = d_in[0];
  const int*  ei_raw = (const int*)d_in[1];

  const int N = in_sizes[0] / FIN;
  const int E = in_sizes[1] / 2;

  // weight-tensor segment offsets (inputs 2..9)
  SegOffs so;
  int acc = 0;
  for (int t = 0; t < 8; ++t) { so.o[t] = acc; acc += in_sizes[t + 2]; }
  so.o[8] = acc;

  char* ws = (char*)d_ws;
  size_t off = 0;
  auto walloc = [&](size_t bytes) -> void* {
    void* p = ws + off;
    off = (off + bytes + 255) & ~(size_t)255;
    return p;
  };
  float* wf      = (float*)walloc((size_t)acc * 4);
  int*   flags   = (int*)walloc(16);
  float* dinv    = (float*)walloc((size_t)N * 4);
  int*   count   = (int*)walloc((size_t)N * 4);
  int*   offs    = (int*)walloc((size_t)(N + 1) * 4);
  int*   cursor  = (int*)walloc((size_t)N * 4);
  int*   partials= (int*)walloc(64 * 4);
  int*   csr_src = (int*)walloc((size_t)E * 4);
  float* csr_w   = (float*)walloc((size_t)E * 4);
  int*   src32   = (int*)walloc((size_t)E * 4);
  int*   dst32   = (int*)walloc((size_t)E * 4);
  float* xagg    = (float*)walloc((size_t)N * FIN * 4);
  float* bufA    = (float*)walloc((size_t)N * HD * 4);
  float* bufB    = (float*)walloc((size_t)N * HD * 4);

  const float* w1f  = wf + so.o[0];
  const float* b1f  = wf + so.o[1];
  const float* w2f  = wf + so.o[2];
  const float* b2f  = wf + so.o[3];
  const float* wh1f = wf + so.o[4];
  const float* bh1f = wf + so.o[5];
  const float* wh2f = wf + so.o[6];
  const float* bh2f = wf + so.o[7];

  detect_kernel<<<1, 256, 0, stream>>>((const unsigned short*)x_raw, ei_raw, flags,
                                       in_sizes[0], in_sizes[1]);

  cvt_w_kernel<<<(acc + 255) / 256, 256, 0, stream>>>(
      d_in[2], d_in[3], d_in[4], d_in[5], d_in[6], d_in[7], d_in[8], d_in[9],
      so, wf, flags);

  hipMemsetAsync(count, 0, (size_t)N * 4, stream);

  const int eb = 256;
  const int eg = (E + eb - 1) / eb;
  edges_count_kernel<<<eg, eb, 0, stream>>>(ei_raw, src32, dst32, E, flags, count);
  dinv_kernel<<<(N + 255) / 256, 256, 0, stream>>>(count, dinv, N);

  const int nb = (N + 255) / 256;
  scan1_kernel<<<nb, 256, 0, stream>>>(count, offs, partials, N);
  scan2_kernel<<<1, 64, 0, stream>>>(partials, offs, nb, N);
  scan3_kernel<<<nb, 256, 0, stream>>>(offs, partials, cursor, N);

  fill_kernel<<<eg, eb, 0, stream>>>(src32, dst32, dinv, cursor, csr_src, csr_w, E);

  const int ab = (N + 3) / 4;  // 4 waves (nodes) per block
  // conv1 (reassociated): xagg = Ahat @ x ; bufA = relu(xagg @ W1 + b1)
  agg1_kernel<<<ab, 256, 0, stream>>>(x_raw, offs, csr_src, csr_w, dinv, xagg, N, flags);
  gemm256<FIN, true,  true ><<<(N + 15) / 16, 256, 0, stream>>>(xagg, w1f, b1f, bufA, N);
  // conv2: bufB = bufA @ W2 ; bufA = relu(Ahat @ bufB + b2)
  gemm256<HD,  false, false><<<(N + 15) / 16, 256, 0, stream>>>(bufA, w2f, nullptr, bufB, N);
  agg2_kernel<<<ab, 256, 0, stream>>>(bufB, offs, csr_src, csr_w, dinv, b2f, bufA, N);
  // dense: bufB = relu(bufA @ Wh1 + bh1)
  gemm256<HD,  true,  true ><<<(N + 15) / 16, 256, 0, stream>>>(bufA, wh1f, bh1f, bufB, N);
  // out = bufB @ Wh2 + bh2
  gemm_out_kernel<<<(N + 31) / 32, 256, 0, stream>>>(bufB, wh2f, bh2f, d_out, N, flags);
}